// Round 1
// baseline (373.194 us; speedup 1.0000x reference)
//
#include <hip/hip_runtime.h>
#include <math.h>

#define NTOK 16384
#define KCB  4096
#define DIM  128

// ---------------------------------------------------------------------------
// ws layout (floats):
//   [0..2]   accum: 0=mse_sum, 1=cos_sum, 2=pair_sum
//   [3]      minbits (as unsigned, +inf initialized)
//   [16 ..)            sumx2 [NTOK]
//   [16+NTOK ..)       sumc2 [KCB]
//   [.. ]              bd2   [2*NTOK]  per-K-split best dist
//   [.. ]              bi2   [2*NTOK]  per-K-split best idx (int)
//   [.. ]              cnt   [KCB]     histogram (int)
// ---------------------------------------------------------------------------

__global__ __launch_bounds__(256) void k_init(float* __restrict__ accum,
                                              unsigned* __restrict__ minbits,
                                              int* __restrict__ cnt) {
  const int t = threadIdx.x;
  if (t < 3) accum[t] = 0.0f;
  if (t == 3) *minbits = 0x7F800000u;  // +inf
  for (int k = t; k < KCB; k += 256) cnt[k] = 0;
}

// Row sum-of-squares in fp64, rounded once to fp32 (stable vs np's pairwise sum).
__global__ __launch_bounds__(256) void k_rownorm(const float* __restrict__ lat,
                                                 const float* __restrict__ cb,
                                                 float* __restrict__ sumx2,
                                                 float* __restrict__ sumc2) {
  const int row  = blockIdx.x * 4 + (threadIdx.x >> 6);
  const int lane = threadIdx.x & 63;
  const float* src = (row < NTOK) ? (lat + (size_t)row * DIM)
                                  : (cb + (size_t)(row - NTOK) * DIM);
  float2 v = *(const float2*)(src + lane * 2);
  double s = (double)v.x * (double)v.x + (double)v.y * (double)v.y;
#pragma unroll
  for (int m = 32; m >= 1; m >>= 1) s += __shfl_xor(s, m, 64);
  if (lane == 0) {
    if (row < NTOK) sumx2[row] = (float)s;
    else            sumc2[row - NTOK] = (float)s;
  }
}

// Fused dist + argmin. Block: 64 tokens x half the codebook (blockIdx.y split).
// dist = fl(fl(sumx2 - 2*s) + sumc2)  — replicates reference fp32 association.
// Strict <  => lowest index wins on ties (codes visited in ascending order).
__global__ __launch_bounds__(256) void k_argmin(const float* __restrict__ lat,
                                                const float* __restrict__ cb,
                                                const float* __restrict__ sumx2,
                                                const float* __restrict__ sumc2,
                                                float* __restrict__ bd2,
                                                int* __restrict__ bi2) {
  __shared__ __align__(16) float A[DIM][64];
  __shared__ __align__(16) float B[DIM][64];
  __shared__ float qs[64];
  __shared__ float red_d[64][17];
  __shared__ int   red_i[64][17];

  const int t  = threadIdx.x;
  const int tx = t & 15, ty = t >> 4;
  const int tok0  = blockIdx.x * 64;
  const int kbase = blockIdx.y * (KCB / 2);

  {  // stage A transposed: A[d][token]
    const int tokl = t & 63;
    const int w = t >> 6;
#pragma unroll
    for (int p = 0; p < 8; ++p) {
      const int dq = w + p * 4;
      float4 v = *(const float4*)(lat + (size_t)(tok0 + tokl) * DIM + dq * 4);
      A[dq * 4 + 0][tokl] = v.x; A[dq * 4 + 1][tokl] = v.y;
      A[dq * 4 + 2][tokl] = v.z; A[dq * 4 + 3][tokl] = v.w;
    }
  }

  float sx[4];
#pragma unroll
  for (int a = 0; a < 4; ++a) sx[a] = sumx2[tok0 + ty * 4 + a];

  float bd[4] = {INFINITY, INFINITY, INFINITY, INFINITY};
  int   bi[4] = {0, 0, 0, 0};

  for (int kt = 0; kt < KCB / 2; kt += 64) {
    __syncthreads();  // protect B (and A on first iter)
    {
      const int cl = t & 63;
      const int w = t >> 6;
#pragma unroll
      for (int p = 0; p < 8; ++p) {
        const int dq = w + p * 4;
        float4 v = *(const float4*)(cb + (size_t)(kbase + kt + cl) * DIM + dq * 4);
        B[dq * 4 + 0][cl] = v.x; B[dq * 4 + 1][cl] = v.y;
        B[dq * 4 + 2][cl] = v.z; B[dq * 4 + 3][cl] = v.w;
      }
      if (t < 64) qs[t] = sumc2[kbase + kt + t];
    }
    __syncthreads();

    float acc[4][4];
#pragma unroll
    for (int a = 0; a < 4; ++a)
#pragma unroll
      for (int b = 0; b < 4; ++b) acc[a][b] = 0.0f;

#pragma unroll 4
    for (int d = 0; d < DIM; ++d) {
      float4 av = *(const float4*)&A[d][ty * 4];
      float4 bv = *(const float4*)&B[d][tx * 4];
      const float aa[4] = {av.x, av.y, av.z, av.w};
      const float bb[4] = {bv.x, bv.y, bv.z, bv.w};
#pragma unroll
      for (int a = 0; a < 4; ++a)
#pragma unroll
        for (int b = 0; b < 4; ++b)
          acc[a][b] = fmaf(aa[a], bb[b], acc[a][b]);
    }

#pragma unroll
    for (int a = 0; a < 4; ++a) {
#pragma unroll
      for (int b = 0; b < 4; ++b) {
        const float dist = (sx[a] - 2.0f * acc[a][b]) + qs[tx * 4 + b];
        const int code = kbase + kt + tx * 4 + b;
        if (dist < bd[a]) { bd[a] = dist; bi[a] = code; }
      }
    }
  }

#pragma unroll
  for (int a = 0; a < 4; ++a) {
    red_d[ty * 4 + a][tx] = bd[a];
    red_i[ty * 4 + a][tx] = bi[a];
  }
  __syncthreads();
  if (t < 64) {
    float best = red_d[t][0];
    int besti  = red_i[t][0];
#pragma unroll
    for (int x = 1; x < 16; ++x) {
      const float dv = red_d[t][x];
      const int iv = red_i[t][x];
      if (dv < best || (dv == best && iv < besti)) { best = dv; besti = iv; }
    }
    bd2[blockIdx.y * NTOK + tok0 + t] = best;
    bi2[blockIdx.y * NTOK + tok0 + t] = besti;
  }
}

// Combine K-splits, gather quantized_st, mse + sel_cos partials, histogram.
__global__ __launch_bounds__(256) void k_gather(const float* __restrict__ lat,
                                                const float* __restrict__ cb,
                                                const float* __restrict__ sumx2,
                                                const float* __restrict__ sumc2,
                                                const float* __restrict__ bd2,
                                                const int* __restrict__ bi2,
                                                float* __restrict__ qout,
                                                float* __restrict__ idx_out,
                                                float* __restrict__ accum,
                                                int* __restrict__ cnt) {
  const int wave = threadIdx.x >> 6, lane = threadIdx.x & 63;
  __shared__ float sm[8];
  float msel = 0.0f, cosl = 0.0f;
  const int base = blockIdx.x * 64 + wave * 16;
  for (int it = 0; it < 16; ++it) {
    const int tok = base + it;
    const float d0 = bd2[tok], d1 = bd2[NTOK + tok];
    const int i0 = bi2[tok], i1 = bi2[NTOK + tok];
    const int code = (d1 < d0) ? i1 : i0;  // tie -> lower half = lower index
    float2 l2 = *(const float2*)(lat + (size_t)tok * DIM + lane * 2);
    float2 c2 = *(const float2*)(cb + (size_t)code * DIM + lane * 2);
    // quantized_st = fl(latent + fl(quantized - latent))
    const float o0 = l2.x + (c2.x - l2.x);
    const float o1 = l2.y + (c2.y - l2.y);
    *(float2*)(qout + (size_t)tok * DIM + lane * 2) = make_float2(o0, o1);
    const float e0 = l2.x - c2.x, e1 = l2.y - c2.y;
    msel += e0 * e0 + e1 * e1;
    float dt = l2.x * c2.x + l2.y * c2.y;
#pragma unroll
    for (int m = 32; m >= 1; m >>= 1) dt += __shfl_xor(dt, m, 64);
    if (lane == 0) {
      const float nx = fmaxf(sqrtf(sumx2[tok]), 1e-12f);
      const float nc = fmaxf(sqrtf(sumc2[code]), 1e-12f);
      cosl += dt / (nx * nc);
      idx_out[tok] = (float)code;
      atomicAdd(&cnt[code], 1);
    }
  }
#pragma unroll
  for (int m = 32; m >= 1; m >>= 1) msel += __shfl_xor(msel, m, 64);
  if (lane == 0) { sm[wave] = msel; sm[4 + wave] = cosl; }
  __syncthreads();
  if (threadIdx.x == 0) {
    atomicAdd(&accum[0], sm[0] + sm[1] + sm[2] + sm[3]);
    atomicAdd(&accum[1], sm[4] + sm[5] + sm[6] + sm[7]);
  }
}

// Codebook pairwise distances: upper-triangular blocks only (x2 for bj<bk).
__global__ __launch_bounds__(256) void k_pair(const float* __restrict__ cb,
                                              const float* __restrict__ sumc2,
                                              float* __restrict__ accum,
                                              unsigned* __restrict__ minbits) {
  const int bj = blockIdx.y, bk = blockIdx.x;
  if (bj > bk) return;
  __shared__ __align__(16) float Cj[DIM][64];
  __shared__ __align__(16) float Ck[DIM][64];
  __shared__ float qj[64], qk[64];
  __shared__ float reds[256];
  const int t = threadIdx.x;
  const int tx = t & 15, ty = t >> 4;
  {
    const int cl = t & 63;
    const int w = t >> 6;
#pragma unroll
    for (int p = 0; p < 8; ++p) {
      const int dq = w + p * 4;
      float4 v = *(const float4*)(cb + (size_t)(bj * 64 + cl) * DIM + dq * 4);
      Cj[dq * 4 + 0][cl] = v.x; Cj[dq * 4 + 1][cl] = v.y;
      Cj[dq * 4 + 2][cl] = v.z; Cj[dq * 4 + 3][cl] = v.w;
      float4 u = *(const float4*)(cb + (size_t)(bk * 64 + cl) * DIM + dq * 4);
      Ck[dq * 4 + 0][cl] = u.x; Ck[dq * 4 + 1][cl] = u.y;
      Ck[dq * 4 + 2][cl] = u.z; Ck[dq * 4 + 3][cl] = u.w;
    }
    if (t < 64) qj[t] = sumc2[bj * 64 + t];
    else if (t < 128) qk[t - 64] = sumc2[bk * 64 + (t - 64)];
  }
  __syncthreads();

  float acc[4][4];
#pragma unroll
  for (int a = 0; a < 4; ++a)
#pragma unroll
    for (int b = 0; b < 4; ++b) acc[a][b] = 0.0f;

#pragma unroll 4
  for (int d = 0; d < DIM; ++d) {
    float4 av = *(const float4*)&Cj[d][ty * 4];
    float4 bv = *(const float4*)&Ck[d][tx * 4];
    const float aa[4] = {av.x, av.y, av.z, av.w};
    const float bb[4] = {bv.x, bv.y, bv.z, bv.w};
#pragma unroll
    for (int a = 0; a < 4; ++a)
#pragma unroll
      for (int b = 0; b < 4; ++b)
        acc[a][b] = fmaf(aa[a], bb[b], acc[a][b]);
  }

  float lsum = 0.0f, lmin = INFINITY;
#pragma unroll
  for (int a = 0; a < 4; ++a) {
#pragma unroll
    for (int b = 0; b < 4; ++b) {
      const int j = bj * 64 + ty * 4 + a;
      const int k = bk * 64 + tx * 4 + b;
      const float d2 = (qj[ty * 4 + a] + qk[tx * 4 + b]) - 2.0f * acc[a][b];
      const float dd = sqrtf(fmaxf(d2, 0.0f));
      lsum += dd;
      if (j != k) lmin = fminf(lmin, dd);
    }
  }
  const float scale = (bj == bk) ? 1.0f : 2.0f;
  reds[t] = lsum;
  __syncthreads();
  for (int s = 128; s >= 1; s >>= 1) {
    if (t < s) reds[t] += reds[t + s];
    __syncthreads();
  }
  if (t == 0) atomicAdd(&accum[2], reds[0] * scale);
  __syncthreads();
  reds[t] = lmin;
  __syncthreads();
  for (int s = 128; s >= 1; s >>= 1) {
    if (t < s) reds[t] = fminf(reds[t], reds[t + s]);
    __syncthreads();
  }
  if (t == 0) atomicMin(minbits, __float_as_uint(reds[0]));
}

__global__ __launch_bounds__(256) void k_final(const int* __restrict__ cnt,
                                               const float* __restrict__ accum,
                                               const unsigned* __restrict__ minbits,
                                               float* __restrict__ outs) {
  __shared__ float sh[256];
  const int t = threadIdx.x;
  float ent = 0.0f;
  for (int k = t; k < KCB; k += 256) {
    const float p = (float)cnt[k] * (1.0f / (float)NTOK);
    ent += p * logf(p + 1e-10f);
  }
  sh[t] = ent;
  __syncthreads();
  for (int s = 128; s >= 1; s >>= 1) {
    if (t < s) sh[t] += sh[t + s];
    __syncthreads();
  }
  if (t == 0) {
    const float mse = accum[0] * (1.0f / (float)(NTOK * DIM));
    outs[0] = 0.25f * mse;                                  // commitment_loss
    outs[1] = mse;                                          // codebook_loss
    outs[2] = expf(-sh[0]);                                 // perplexity
    outs[3] = accum[1] * (1.0f / (float)NTOK);              // sel_cos
    outs[4] = accum[2] / ((float)KCB * (float)(KCB - 1));   // avg_euclidean
    outs[5] = __uint_as_float(*minbits);                    // min_euclidean
  }
}

extern "C" void kernel_launch(void* const* d_in, const int* in_sizes, int n_in,
                              void* d_out, int out_size, void* d_ws, size_t ws_size,
                              hipStream_t stream) {
  const float* lat = (const float*)d_in[0];
  const float* cb  = (const float*)d_in[1];

  float* out     = (float*)d_out;
  float* qout    = out;
  float* idx_out = out + (size_t)NTOK * DIM;
  float* outs    = idx_out + NTOK;

  float* W       = (float*)d_ws;
  float* accum   = W;                       // 3 floats
  unsigned* minb = (unsigned*)(W + 3);
  float* sumx2   = W + 16;                  // NTOK
  float* sumc2   = sumx2 + NTOK;            // KCB
  float* bd2     = sumc2 + KCB;             // 2*NTOK
  int*   bi2     = (int*)(bd2 + 2 * NTOK);  // 2*NTOK
  int*   cnt     = bi2 + 2 * NTOK;          // KCB

  hipLaunchKernelGGL(k_init, dim3(1), dim3(256), 0, stream, accum, minb, cnt);
  hipLaunchKernelGGL(k_rownorm, dim3((NTOK + KCB) / 4), dim3(256), 0, stream,
                     lat, cb, sumx2, sumc2);
  hipLaunchKernelGGL(k_argmin, dim3(NTOK / 64, 2), dim3(256), 0, stream,
                     lat, cb, sumx2, sumc2, bd2, bi2);
  hipLaunchKernelGGL(k_gather, dim3(NTOK / 64), dim3(256), 0, stream,
                     lat, cb, sumx2, sumc2, bd2, bi2, qout, idx_out, accum, cnt);
  hipLaunchKernelGGL(k_pair, dim3(KCB / 64, KCB / 64), dim3(256), 0, stream,
                     cb, sumc2, accum, minb);
  hipLaunchKernelGGL(k_final, dim3(1), dim3(256), 0, stream, cnt, accum, minb, outs);
}

// Round 2
// 332.547 us; speedup vs baseline: 1.1222x; 1.1222x over previous
//
#include <hip/hip_runtime.h>
#include <math.h>

#define NTOK 16384
#define KCB  4096
#define DIM  128
#define TILE 128          // token/code tile per block
#define KSPLIT 4
#define KPB (KCB / KSPLIT)

// ---------------------------------------------------------------------------
// ws layout (floats):
//   [0..2]   accum: 0=mse_sum, 1=cos_sum, 2=pair_sum
//   [3]      minbits (as unsigned, +inf initialized)
//   [16 ..)            sumx2 [NTOK]
//   [..]               sumc2 [KCB]
//   [..]               bd2   [KSPLIT*NTOK]
//   [..]               bi2   [KSPLIT*NTOK] (int)
//   [..]               cnt   [KCB] (int)
// ---------------------------------------------------------------------------

__global__ __launch_bounds__(256) void k_init(float* __restrict__ accum,
                                              unsigned* __restrict__ minbits,
                                              int* __restrict__ cnt) {
  const int t = threadIdx.x;
  if (t < 3) accum[t] = 0.0f;
  if (t == 3) *minbits = 0x7F800000u;  // +inf
  for (int k = t; k < KCB; k += 256) cnt[k] = 0;
}

// Row sum-of-squares in fp64, rounded once to fp32.
__global__ __launch_bounds__(256) void k_rownorm(const float* __restrict__ lat,
                                                 const float* __restrict__ cb,
                                                 float* __restrict__ sumx2,
                                                 float* __restrict__ sumc2) {
  const int row  = blockIdx.x * 4 + (threadIdx.x >> 6);
  const int lane = threadIdx.x & 63;
  const float* src = (row < NTOK) ? (lat + (size_t)row * DIM)
                                  : (cb + (size_t)(row - NTOK) * DIM);
  float2 v = *(const float2*)(src + lane * 2);
  double s = (double)v.x * (double)v.x + (double)v.y * (double)v.y;
#pragma unroll
  for (int m = 32; m >= 1; m >>= 1) s += __shfl_xor(s, m, 64);
  if (lane == 0) {
    if (row < NTOK) sumx2[row] = (float)s;
    else            sumc2[row - NTOK] = (float)s;
  }
}

// Fused dist + argmin. 128 tokens x 128 codes per block, 8x8 per thread.
// dist = fl(fl(sumx2 - 2*s) + sumc2) with d accumulated 0..127 sequentially
// => bitwise-identical to the round-1 kernel (which passed).
__global__ __launch_bounds__(256, 2) void k_argmin(const float* __restrict__ lat,
                                                   const float* __restrict__ cb,
                                                   const float* __restrict__ sumx2,
                                                   const float* __restrict__ sumc2,
                                                   float* __restrict__ bd2,
                                                   int* __restrict__ bi2) {
  __shared__ __align__(16) unsigned char smem[66560];
  float (*As)[TILE] = (float (*)[TILE])smem;              // [64][128]
  float (*Bs)[TILE] = (float (*)[TILE])(smem + 32768);    // [64][128]
  float* qs = (float*)(smem + 65536);                     // [128]

  const int t  = threadIdx.x;
  const int tx = t & 15, ty = t >> 4;         // 16x16 thread grid
  const int tok0  = blockIdx.x * TILE;
  const int kbase = blockIdx.y * KPB;
  const int r_stage = t & 127;
  const int h_stage = t >> 7;                 // 0/1: which 32-dim half

  float sx[8];
#pragma unroll
  for (int a = 0; a < 8; ++a)
    sx[a] = sumx2[tok0 + ty * 4 + (a & 3) + ((a >> 2) << 6)];

  float bd[8];
  int   bi[8];
#pragma unroll
  for (int a = 0; a < 8; ++a) { bd[a] = INFINITY; bi[a] = 0; }

  for (int kt = 0; kt < KPB; kt += TILE) {
    float acc[8][8];
#pragma unroll
    for (int a = 0; a < 8; ++a)
#pragma unroll
      for (int b = 0; b < 8; ++b) acc[a][b] = 0.0f;

    for (int dc = 0; dc < DIM; dc += 64) {
      __syncthreads();
      {  // stage As, Bs transposed: [d][row]
        const float* asrc = lat + (size_t)(tok0 + r_stage) * DIM + dc + h_stage * 32;
#pragma unroll
        for (int p = 0; p < 8; ++p) {
          float4 v = *(const float4*)(asrc + p * 4);
          const int d = h_stage * 32 + p * 4;
          As[d + 0][r_stage] = v.x; As[d + 1][r_stage] = v.y;
          As[d + 2][r_stage] = v.z; As[d + 3][r_stage] = v.w;
        }
        const float* bsrc = cb + (size_t)(kbase + kt + r_stage) * DIM + dc + h_stage * 32;
#pragma unroll
        for (int p = 0; p < 8; ++p) {
          float4 v = *(const float4*)(bsrc + p * 4);
          const int d = h_stage * 32 + p * 4;
          Bs[d + 0][r_stage] = v.x; Bs[d + 1][r_stage] = v.y;
          Bs[d + 2][r_stage] = v.z; Bs[d + 3][r_stage] = v.w;
        }
        if (dc == 0 && t < TILE) qs[t] = sumc2[kbase + kt + t];
      }
      __syncthreads();

#pragma unroll 4
      for (int d = 0; d < 64; ++d) {
        float4 a0 = *(const float4*)&As[d][ty * 4];
        float4 a1 = *(const float4*)&As[d][64 + ty * 4];
        float4 b0 = *(const float4*)&Bs[d][tx * 4];
        float4 b1 = *(const float4*)&Bs[d][64 + tx * 4];
        const float aa[8] = {a0.x, a0.y, a0.z, a0.w, a1.x, a1.y, a1.z, a1.w};
        const float bb[8] = {b0.x, b0.y, b0.z, b0.w, b1.x, b1.y, b1.z, b1.w};
#pragma unroll
        for (int a = 0; a < 8; ++a)
#pragma unroll
          for (int b = 0; b < 8; ++b)
            acc[a][b] = fmaf(aa[a], bb[b], acc[a][b]);
      }
    }

    // epilogue: codes visited in ascending order within thread; strict <
#pragma unroll
    for (int a = 0; a < 8; ++a) {
#pragma unroll
      for (int b = 0; b < 8; ++b) {
        const int cl = tx * 4 + (b & 3) + ((b >> 2) << 6);
        const float dist = (sx[a] - 2.0f * acc[a][b]) + qs[cl];
        if (dist < bd[a]) { bd[a] = dist; bi[a] = kbase + kt + cl; }
      }
    }
  }

  __syncthreads();
  // overlay per-row reduction arrays on As/Bs space
  float (*red_d)[17] = (float (*)[17])smem;               // [128][17]
  int   (*red_i)[17] = (int   (*)[17])(smem + 16384);
#pragma unroll
  for (int a = 0; a < 8; ++a) {
    const int row = ty * 4 + (a & 3) + ((a >> 2) << 6);
    red_d[row][tx] = bd[a];
    red_i[row][tx] = bi[a];
  }
  __syncthreads();
  if (t < TILE) {
    float best = red_d[t][0];
    int besti  = red_i[t][0];
#pragma unroll
    for (int x = 1; x < 16; ++x) {
      const float dv = red_d[t][x];
      const int iv = red_i[t][x];
      if (dv < best || (dv == best && iv < besti)) { best = dv; besti = iv; }
    }
    bd2[blockIdx.y * NTOK + tok0 + t] = best;
    bi2[blockIdx.y * NTOK + tok0 + t] = besti;
  }
}

// Combine K-splits, gather quantized_st, mse + sel_cos partials, histogram.
__global__ __launch_bounds__(256) void k_gather(const float* __restrict__ lat,
                                                const float* __restrict__ cb,
                                                const float* __restrict__ sumx2,
                                                const float* __restrict__ sumc2,
                                                const float* __restrict__ bd2,
                                                const int* __restrict__ bi2,
                                                float* __restrict__ qout,
                                                float* __restrict__ idx_out,
                                                float* __restrict__ accum,
                                                int* __restrict__ cnt) {
  const int wave = threadIdx.x >> 6, lane = threadIdx.x & 63;
  __shared__ float sm[8];
  float msel = 0.0f, cosl = 0.0f;
  const int base = blockIdx.x * 64 + wave * 16;
  for (int it = 0; it < 16; ++it) {
    const int tok = base + it;
    float best = bd2[tok];
    int code   = bi2[tok];
#pragma unroll
    for (int s = 1; s < KSPLIT; ++s) {
      const float dv = bd2[s * NTOK + tok];
      const int iv = bi2[s * NTOK + tok];
      if (dv < best) { best = dv; code = iv; }  // tie -> lower split = lower idx
    }
    float2 l2 = *(const float2*)(lat + (size_t)tok * DIM + lane * 2);
    float2 c2 = *(const float2*)(cb + (size_t)code * DIM + lane * 2);
    const float o0 = l2.x + (c2.x - l2.x);
    const float o1 = l2.y + (c2.y - l2.y);
    *(float2*)(qout + (size_t)tok * DIM + lane * 2) = make_float2(o0, o1);
    const float e0 = l2.x - c2.x, e1 = l2.y - c2.y;
    msel += e0 * e0 + e1 * e1;
    float dt = l2.x * c2.x + l2.y * c2.y;
#pragma unroll
    for (int m = 32; m >= 1; m >>= 1) dt += __shfl_xor(dt, m, 64);
    if (lane == 0) {
      const float nx = fmaxf(sqrtf(sumx2[tok]), 1e-12f);
      const float nc = fmaxf(sqrtf(sumc2[code]), 1e-12f);
      cosl += dt / (nx * nc);
      idx_out[tok] = (float)code;
      atomicAdd(&cnt[code], 1);
    }
  }
#pragma unroll
  for (int m = 32; m >= 1; m >>= 1) msel += __shfl_xor(msel, m, 64);
  if (lane == 0) { sm[wave] = msel; sm[4 + wave] = cosl; }
  __syncthreads();
  if (threadIdx.x == 0) {
    atomicAdd(&accum[0], sm[0] + sm[1] + sm[2] + sm[3]);
    atomicAdd(&accum[1], sm[4] + sm[5] + sm[6] + sm[7]);
  }
}

// Codebook pairwise distances: 128x128 tiles, upper-triangular (x2 off-diag).
__global__ __launch_bounds__(256, 2) void k_pair(const float* __restrict__ cb,
                                                 const float* __restrict__ sumc2,
                                                 float* __restrict__ accum,
                                                 unsigned* __restrict__ minbits) {
  const int bj = blockIdx.y, bk = blockIdx.x;
  if (bj > bk) return;
  __shared__ __align__(16) unsigned char smem[66560 + 512];
  float (*Cj)[TILE] = (float (*)[TILE])smem;
  float (*Ck)[TILE] = (float (*)[TILE])(smem + 32768);
  float* qj = (float*)(smem + 65536);   // [128]
  float* qk = (float*)(smem + 66048);   // [128]

  const int t  = threadIdx.x;
  const int tx = t & 15, ty = t >> 4;
  const int r_stage = t & 127;
  const int h_stage = t >> 7;

  float acc[8][8];
#pragma unroll
  for (int a = 0; a < 8; ++a)
#pragma unroll
    for (int b = 0; b < 8; ++b) acc[a][b] = 0.0f;

  for (int dc = 0; dc < DIM; dc += 64) {
    __syncthreads();
    {
      const float* jsrc = cb + (size_t)(bj * TILE + r_stage) * DIM + dc + h_stage * 32;
#pragma unroll
      for (int p = 0; p < 8; ++p) {
        float4 v = *(const float4*)(jsrc + p * 4);
        const int d = h_stage * 32 + p * 4;
        Cj[d + 0][r_stage] = v.x; Cj[d + 1][r_stage] = v.y;
        Cj[d + 2][r_stage] = v.z; Cj[d + 3][r_stage] = v.w;
      }
      const float* ksrc = cb + (size_t)(bk * TILE + r_stage) * DIM + dc + h_stage * 32;
#pragma unroll
      for (int p = 0; p < 8; ++p) {
        float4 v = *(const float4*)(ksrc + p * 4);
        const int d = h_stage * 32 + p * 4;
        Ck[d + 0][r_stage] = v.x; Ck[d + 1][r_stage] = v.y;
        Ck[d + 2][r_stage] = v.z; Ck[d + 3][r_stage] = v.w;
      }
      if (dc == 0) {
        if (t < TILE) qj[t] = sumc2[bj * TILE + t];
        else          qk[t - TILE] = sumc2[bk * TILE + (t - TILE)];
      }
    }
    __syncthreads();

#pragma unroll 4
    for (int d = 0; d < 64; ++d) {
      float4 a0 = *(const float4*)&Cj[d][ty * 4];
      float4 a1 = *(const float4*)&Cj[d][64 + ty * 4];
      float4 b0 = *(const float4*)&Ck[d][tx * 4];
      float4 b1 = *(const float4*)&Ck[d][64 + tx * 4];
      const float aa[8] = {a0.x, a0.y, a0.z, a0.w, a1.x, a1.y, a1.z, a1.w};
      const float bb[8] = {b0.x, b0.y, b0.z, b0.w, b1.x, b1.y, b1.z, b1.w};
#pragma unroll
      for (int a = 0; a < 8; ++a)
#pragma unroll
        for (int b = 0; b < 8; ++b)
          acc[a][b] = fmaf(aa[a], bb[b], acc[a][b]);
    }
  }

  float lsum = 0.0f, lmin = INFINITY;
#pragma unroll
  for (int a = 0; a < 8; ++a) {
#pragma unroll
    for (int b = 0; b < 8; ++b) {
      const int jl = ty * 4 + (a & 3) + ((a >> 2) << 6);
      const int kl = tx * 4 + (b & 3) + ((b >> 2) << 6);
      const int j = bj * TILE + jl;
      const int k = bk * TILE + kl;
      const float d2 = (qj[jl] + qk[kl]) - 2.0f * acc[a][b];
      const float dd = sqrtf(fmaxf(d2, 0.0f));
      lsum += dd;
      if (j != k) lmin = fminf(lmin, dd);
    }
  }
  const float scale = (bj == bk) ? 1.0f : 2.0f;

  __syncthreads();
  float* reds = (float*)smem;
  reds[t] = lsum;
  __syncthreads();
  for (int s = 128; s >= 1; s >>= 1) {
    if (t < s) reds[t] += reds[t + s];
    __syncthreads();
  }
  if (t == 0) atomicAdd(&accum[2], reds[0] * scale);
  __syncthreads();
  reds[t] = lmin;
  __syncthreads();
  for (int s = 128; s >= 1; s >>= 1) {
    if (t < s) reds[t] = fminf(reds[t], reds[t + s]);
    __syncthreads();
  }
  if (t == 0) atomicMin(minbits, __float_as_uint(reds[0]));
}

__global__ __launch_bounds__(256) void k_final(const int* __restrict__ cnt,
                                               const float* __restrict__ accum,
                                               const unsigned* __restrict__ minbits,
                                               float* __restrict__ outs) {
  __shared__ float sh[256];
  const int t = threadIdx.x;
  float ent = 0.0f;
  for (int k = t; k < KCB; k += 256) {
    const float p = (float)cnt[k] * (1.0f / (float)NTOK);
    ent += p * logf(p + 1e-10f);
  }
  sh[t] = ent;
  __syncthreads();
  for (int s = 128; s >= 1; s >>= 1) {
    if (t < s) sh[t] += sh[t + s];
    __syncthreads();
  }
  if (t == 0) {
    const float mse = accum[0] * (1.0f / (float)(NTOK * DIM));
    outs[0] = 0.25f * mse;
    outs[1] = mse;
    outs[2] = expf(-sh[0]);
    outs[3] = accum[1] * (1.0f / (float)NTOK);
    outs[4] = accum[2] / ((float)KCB * (float)(KCB - 1));
    outs[5] = __uint_as_float(*minbits);
  }
}

extern "C" void kernel_launch(void* const* d_in, const int* in_sizes, int n_in,
                              void* d_out, int out_size, void* d_ws, size_t ws_size,
                              hipStream_t stream) {
  const float* lat = (const float*)d_in[0];
  const float* cb  = (const float*)d_in[1];

  float* out     = (float*)d_out;
  float* qout    = out;
  float* idx_out = out + (size_t)NTOK * DIM;
  float* outs    = idx_out + NTOK;

  float* W       = (float*)d_ws;
  float* accum   = W;                            // 3 floats
  unsigned* minb = (unsigned*)(W + 3);
  float* sumx2   = W + 16;                       // NTOK
  float* sumc2   = sumx2 + NTOK;                 // KCB
  float* bd2     = sumc2 + KCB;                  // KSPLIT*NTOK
  int*   bi2     = (int*)(bd2 + KSPLIT * NTOK);  // KSPLIT*NTOK
  int*   cnt     = bi2 + KSPLIT * NTOK;          // KCB

  hipLaunchKernelGGL(k_init, dim3(1), dim3(256), 0, stream, accum, minb, cnt);
  hipLaunchKernelGGL(k_rownorm, dim3((NTOK + KCB) / 4), dim3(256), 0, stream,
                     lat, cb, sumx2, sumc2);
  hipLaunchKernelGGL(k_argmin, dim3(NTOK / TILE, KSPLIT), dim3(256), 0, stream,
                     lat, cb, sumx2, sumc2, bd2, bi2);
  hipLaunchKernelGGL(k_gather, dim3(NTOK / 64), dim3(256), 0, stream,
                     lat, cb, sumx2, sumc2, bd2, bi2, qout, idx_out, accum, cnt);
  hipLaunchKernelGGL(k_pair, dim3(KCB / TILE, KCB / TILE), dim3(256), 0, stream,
                     cb, sumc2, accum, minb);
  hipLaunchKernelGGL(k_final, dim3(1), dim3(256), 0, stream, cnt, accum, minb, outs);
}